// Round 2
// baseline (4341.747 us; speedup 1.0000x reference)
//
#include <hip/hip_runtime.h>
#include <hip/hip_cooperative_groups.h>

namespace cg = cooperative_groups;

static constexpr int N    = 2048;
static constexpr int BS   = 32;
static constexpr int NBLK = 256;        // 1 block / CU
static constexpr int TPB  = 512;        // 8 waves / CU
static constexpr int ROWS = N / NBLK;   // 8 rows per block
static constexpr int KG   = TPB / BS;   // 16 k-groups
static constexpr int KSL  = N / KG;     // 128 k per group
static constexpr float OMEGA_F = 2.0f / 3.0f;

// ws layout (floats):
//   slots : [0, (maxiter+1)*BS)  -> ||r_j||^2 accumulators (65*32 = 2080)
//   bsum  : [2080, 2112)         -> ||b||^2 per batch
//   thr2  : [2112, 2144)         -> (rtol*bnorm)^2 (or -1 => always continue)
//   dinv  : [2144, 4192)         -> 1/diag(A)
//   RT    : [4192, 4192+BS*N)    -> residual r, [b][k] layout
//   ST    : [+BS*N)              -> omega*dinv*r, [b][k] layout (next matmul input)

__global__ __launch_bounds__(TPB) void jacobi_kernel(
    const float* __restrict__ A, const float* __restrict__ bvec,
    const float* __restrict__ rtol, const float* __restrict__ theta,
    float* __restrict__ out, float* __restrict__ ws, int maxiter)
{
  cg::grid_group grid = cg::this_grid();
  const int tid  = threadIdx.x;
  const int bid  = blockIdx.x;
  const int gtid = bid * TPB + tid;

  float* slots = ws;
  float* bsum  = ws + 2080;
  float* thr2  = ws + 2112;
  float* dinv  = ws + 2144;
  float* RT    = ws + 4192;
  float* ST    = ws + 4192 + BS * N;

  // ---- phase 0: zero accumulators (ws is poisoned 0xAA each call), dinv ----
  if (bid == 0) {
    for (int i = tid; i < (maxiter + 1) * BS + BS; i += TPB) ws[i] = 0.0f;
  }
  if (gtid < N) dinv[gtid] = 1.0f / A[gtid * N + gtid];
  grid.sync();

  // ---- phase 1: ||b||^2 per batch (wave shuffle reduce, 1 atomic/wave) ----
  if (gtid < BS * N) {
    const int b = gtid >> 11;          // gtid = b*N + k, wave spans same b
    float v = bvec[gtid];
    float s = v * v;
    #pragma unroll
    for (int off = 32; off; off >>= 1) s += __shfl_down(s, off, 64);
    if ((tid & 63) == 0) atomicAdd(&bsum[b], s);
  }
  grid.sync();

  // ---- main loop: j==0 computes r0 = b - A*theta; j>=1: r' = r - A*(w*dinv*r) ----
  __shared__ float red[TPB * ROWS];    // 16 KB split-K partials
  __shared__ float nred[BS];
  __shared__ int contf;

  const int kg = tid >> 5;
  const int bb = tid & (BS - 1);
  const int r0 = bid * ROWS;
  const int k0 = kg * KSL;

  for (int j = 0; j <= maxiter; ++j) {
    if (tid == 0) {
      int c = 1;
      if (j >= 1) {
        c = 0;
        for (int b2 = 0; b2 < BS; ++b2)
          c |= (slots[(j - 1) * BS + b2] > thr2[b2]) ? 1 : 0;
      }
      contf = c;
    }
    if (tid < BS) nred[tid] = 0.0f;
    __syncthreads();

    if (contf) {
      const float* __restrict__ vin  = (j == 0) ? theta : ST;  // [b][k]
      const float* __restrict__ prev = (j == 0) ? bvec  : RT;  // [b][k]

      float acc[ROWS];
      #pragma unroll
      for (int i = 0; i < ROWS; ++i) acc[i] = 0.0f;

      const float* vrow = vin + bb * N;
      const float* arow = A + (size_t)r0 * N;
      for (int k = k0; k < k0 + KSL; k += 4) {
        const float4 s4 = *(const float4*)(vrow + k);
        #pragma unroll
        for (int i = 0; i < ROWS; ++i) {
          const float4 a4 = *(const float4*)(arow + i * N + k);
          acc[i] = fmaf(a4.x, s4.x, acc[i]);
          acc[i] = fmaf(a4.y, s4.y, acc[i]);
          acc[i] = fmaf(a4.z, s4.z, acc[i]);
          acc[i] = fmaf(a4.w, s4.w, acc[i]);
        }
      }
      #pragma unroll
      for (int i = 0; i < ROWS; ++i) red[tid * ROWS + i] = acc[i];
      __syncthreads();

      // 128 reducers: (b2, ih) -> rows 2ih, 2ih+1; sum 16 k-group partials
      if (tid < BS * 4) {
        const int b2 = tid & (BS - 1);
        const int ih = tid >> 5;
        float t0 = 0.0f, t1 = 0.0f;
        #pragma unroll
        for (int g = 0; g < KG; ++g) {
          const int base = ((g << 5) | b2) * ROWS + (ih << 1);
          t0 += red[base];
          t1 += red[base + 1];
        }
        const int r = r0 + (ih << 1);
        const float rn0 = prev[b2 * N + r]     - t0;
        const float rn1 = prev[b2 * N + r + 1] - t1;
        RT[b2 * N + r]     = rn0;
        RT[b2 * N + r + 1] = rn1;
        ST[b2 * N + r]     = OMEGA_F * dinv[r]     * rn0;
        ST[b2 * N + r + 1] = OMEGA_F * dinv[r + 1] * rn1;
        atomicAdd(&nred[b2], rn0 * rn0 + rn1 * rn1);
      }
      // piggyback: thr2 written once (needs bsum, ready after phase-1 sync)
      if (j == 0 && bid == 0 && tid >= TPB - BS) {
        const int b2 = tid - (TPB - BS);
        const float rt = rtol[b2];
        thr2[b2] = (rt >= 0.0f) ? rt * rt * bsum[b2] : -1.0f;
      }
      __syncthreads();
      if (tid < BS) atomicAdd(&slots[j * BS + tid], nred[tid]);
    }
    grid.sync();
  }

  // ---- output: out[b][t], t=0 -> crit0, t>=1 -> cont_t ? crit_t : 0 ----
  if (bid == 0) {
    __shared__ int contseq[72];
    if (tid >= 1 && tid <= maxiter) {
      int c = 0;
      for (int b2 = 0; b2 < BS; ++b2)
        c |= (slots[(tid - 1) * BS + b2] > thr2[b2]) ? 1 : 0;
      contseq[tid] = c;
    }
    __syncthreads();
    if (tid == 0) {
      int run = 1;
      for (int t = 1; t <= maxiter; ++t) { run &= contseq[t]; contseq[t] = run; }
    }
    __syncthreads();
    const int M1 = maxiter + 1;
    for (int idx = tid; idx < BS * M1; idx += TPB) {
      const int b2 = idx / M1;
      const int t  = idx % M1;
      const float bn = sqrtf(bsum[b2]);
      float val;
      if (t == 0) val = sqrtf(slots[b2]) / bn;
      else val = contseq[t] ? (sqrtf(slots[t * BS + b2]) / bn) : 0.0f;
      out[idx] = val;
    }
  }
}

extern "C" void kernel_launch(void* const* d_in, const int* in_sizes, int n_in,
                              void* d_out, int out_size, void* d_ws, size_t ws_size,
                              hipStream_t stream)
{
  (void)n_in; (void)ws_size;
  const float* A     = (const float*)d_in[0];   // use only A[0] slice (ref: A[:1])
  const float* bvec  = (const float*)d_in[1];
  const float* rtol  = (const float*)d_in[3];   // d_in[2] = x_sol, unused by ref
  const float* theta = (const float*)d_in[4];
  float* out = (float*)d_out;
  float* ws  = (float*)d_ws;
  const int bs = in_sizes[3];                   // 32
  const int maxiter = out_size / bs - 1;        // 64

  void* args[] = { (void*)&A, (void*)&bvec, (void*)&rtol, (void*)&theta,
                   (void*)&out, (void*)&ws, (void*)&maxiter };
  hipLaunchCooperativeKernel((void*)jacobi_kernel, dim3(NBLK), dim3(TPB),
                             args, 0, stream);
}

// Round 3
// 2920.269 us; speedup vs baseline: 1.4868x; 1.4868x over previous
//
#include <hip/hip_runtime.h>
#include <hip/hip_cooperative_groups.h>

static constexpr int N    = 2048;
static constexpr int BS   = 32;
static constexpr int NBLK = 256;        // 1 block / CU
static constexpr int TPB  = 512;        // 8 waves / CU
static constexpr int ROWS = 8;          // rows per block
static constexpr int KG   = 16;         // k-groups per block
static constexpr int KSL  = 128;        // k per group
static constexpr int SLOT_STRIDE = 80;  // floats between batches' slot rows (320 B)
static constexpr float OMEGA_F = 2.0f / 3.0f;

// ws float offsets
static constexpr int WS_SLOTS = 0;      // 32 x SLOT_STRIDE : ||r_j||^2, [b][j]
static constexpr int WS_CNT   = 2560;   // 32 uint counters, stride 32 (128 B)
static constexpr int WS_REL   = 3584;   // release generation flag (uint)
static constexpr int WS_BSUM  = 3616;   // 32 : ||b||^2
static constexpr int WS_ST0   = 4096;   // 65536 : x / omega*dinv*r, [k][b]
static constexpr int WS_ST1   = 69632;  // 65536 : ping-pong partner
static constexpr int WS_ZERO_BYTES = 3648 * 4;   // memset range: slots+cnt+rel

// Hierarchical grid barrier: 256 arrivals over 32 padded lines (8 RMW each),
// block 0 wave 0 polls, single release flag, waiters poll relaxed + 1 acquire.
__device__ __forceinline__ void gbar(unsigned* cnt, unsigned* rel, unsigned gen,
                                     int bid, int tid) {
  __syncthreads();
  if (tid == 0)
    __hip_atomic_fetch_add(&cnt[(bid & 31) << 5], 1u,
                           __ATOMIC_RELEASE, __HIP_MEMORY_SCOPE_AGENT);
  if (bid == 0) {
    if (tid < 32) {
      int guard = 0;
      while (__hip_atomic_load(&cnt[tid << 5], __ATOMIC_RELAXED,
                               __HIP_MEMORY_SCOPE_AGENT) < 8u * gen) {
        __builtin_amdgcn_s_sleep(1);
        if (++guard > (1 << 30)) break;   // failsafe: fail loud, don't hang
      }
    }
    if (tid == 0)
      __hip_atomic_store(rel, gen, __ATOMIC_RELEASE, __HIP_MEMORY_SCOPE_AGENT);
  } else if (tid == 0) {
    int guard = 0;
    while (__hip_atomic_load(rel, __ATOMIC_RELAXED,
                             __HIP_MEMORY_SCOPE_AGENT) < gen) {
      __builtin_amdgcn_s_sleep(2);
      if (++guard > (1 << 30)) break;
    }
  }
  if (tid == 0) __builtin_amdgcn_fence(__ATOMIC_ACQUIRE, "agent");
  __syncthreads();
}

__global__ __launch_bounds__(TPB) void jacobi_kernel(
    const float* __restrict__ A, const float* __restrict__ bvec,
    const float* __restrict__ rtol, const float* __restrict__ theta,
    float* __restrict__ out, float* __restrict__ ws, int maxiter)
{
  const int tid = threadIdx.x;
  const int bid = blockIdx.x;

  float*    slots = ws + WS_SLOTS;
  unsigned* cnt   = (unsigned*)(ws + WS_CNT);
  unsigned* rel   = (unsigned*)(ws + WS_REL);
  float*    bsum  = ws + WS_BSUM;
  float*    ST0   = ws + WS_ST0;
  float*    ST1   = ws + WS_ST1;

  __shared__ float red[TPB * ROWS];   // 16 KB split-K partials
  __shared__ float dinv_l[ROWS];
  __shared__ float thr2_l[BS];
  __shared__ float wsum[8];
  __shared__ int   cf_l;

  const int bb = tid & 31;
  const int kg = tid >> 5;
  const int r0 = bid * ROWS;
  const int k0 = kg * KSL;

  // ---- init (no grid sync needed; control region zeroed by memset) ----
  if (tid < ROWS)
    dinv_l[tid] = 1.0f / A[(size_t)(r0 + tid) * N + (r0 + tid)];
  if (tid < 256) {                       // theta -> ST0 transposed [k][b]
    const int b = tid & 31, ks = tid >> 5;   // ks in 0..7
    ST0[(r0 + ks) * 32 + b] = theta[(size_t)b * N + r0 + ks];
  }
  if (bid < BS) {                        // ||b||^2, block i -> batch i
    const float4 v = ((const float4*)(bvec + (size_t)bid * N))[tid];
    float s = v.x * v.x + v.y * v.y + v.z * v.z + v.w * v.w;
    #pragma unroll
    for (int off = 32; off; off >>= 1) s += __shfl_down(s, off, 64);
    if ((tid & 63) == 0) wsum[tid >> 6] = s;
    __syncthreads();
    if (tid == 0) {
      float t = 0.0f;
      #pragma unroll
      for (int w = 0; w < 8; ++w) t += wsum[w];
      bsum[bid] = t;
    }
  }
  gbar(cnt, rel, 1u, bid, tid);

  // ---- main loop: r' = r - A*(omega*dinv*r), one barrier per iteration ----
  float rcur0 = 0.0f, rcur1 = 0.0f;      // carried residual (tid<128 reducers)
  for (int j = 0; j <= maxiter; ++j) {
    // speculative early slot load for the continue check (hidden under matvec)
    float sv = 0.0f;
    if (j >= 1 && tid < 32) {
      if (j == 1) {
        const float rt = rtol[tid];
        thr2_l[tid] = (rt >= 0.0f) ? rt * rt * bsum[tid] : -1.0f;
      }
      sv = slots[tid * SLOT_STRIDE + (j - 1)];
    }

    const float* __restrict__ vin  = (j & 1) ? ST1 : ST0;
    float* __restrict__       vout = (j & 1) ? ST0 : ST1;

    float acc[ROWS];
    #pragma unroll
    for (int i = 0; i < ROWS; ++i) acc[i] = 0.0f;

    const float* arow = A + (size_t)r0 * N;
    for (int k = k0; k < k0 + KSL; k += 4) {
      const float s0 = vin[(k + 0) * 32 + bb];   // coalesced: lanes = consecutive b
      const float s1 = vin[(k + 1) * 32 + bb];
      const float s2 = vin[(k + 2) * 32 + bb];
      const float s3 = vin[(k + 3) * 32 + bb];
      #pragma unroll
      for (int i = 0; i < ROWS; ++i) {
        const float4 a4 = *(const float4*)(arow + (size_t)i * N + k);  // bcast
        acc[i] = fmaf(a4.x, s0, acc[i]);
        acc[i] = fmaf(a4.y, s1, acc[i]);
        acc[i] = fmaf(a4.z, s2, acc[i]);
        acc[i] = fmaf(a4.w, s3, acc[i]);
      }
    }

    // resolve continue flag (wave 0) — gates only the WRITES below
    if (j >= 1) {
      if (tid < 64) {
        bool pred = false;
        if (tid < 32) pred = sv > thr2_l[tid];
        const unsigned long long m = __ballot(pred);
        if (tid == 0) cf_l = (m != 0ull) ? 1 : 0;
      }
    } else if (tid == 0) cf_l = 1;

    #pragma unroll
    for (int i = 0; i < ROWS; ++i) red[tid * ROWS + i] = acc[i];
    __syncthreads();

    if (cf_l && tid < 128) {
      const int b2 = tid & 31, ih = tid >> 5;
      float t0 = 0.0f, t1 = 0.0f;
      #pragma unroll
      for (int g = 0; g < KG; ++g) {
        const int base = ((g << 5) | b2) * ROWS + (ih << 1);
        t0 += red[base];
        t1 += red[base + 1];
      }
      const int r = r0 + (ih << 1);
      float p0, p1;
      if (j == 0) {                       // r0 = b - A*theta
        p0 = bvec[(size_t)b2 * N + r];
        p1 = bvec[(size_t)b2 * N + r + 1];
      } else { p0 = rcur0; p1 = rcur1; }
      const float rn0 = p0 - t0, rn1 = p1 - t1;
      rcur0 = rn0; rcur1 = rn1;
      vout[(r)     * 32 + b2] = OMEGA_F * dinv_l[(ih << 1)]     * rn0;  // coalesced
      vout[(r + 1) * 32 + b2] = OMEGA_F * dinv_l[(ih << 1) + 1] * rn1;
      atomicAdd(&slots[b2 * SLOT_STRIDE + j], rn0 * rn0 + rn1 * rn1);
    }
    gbar(cnt, rel, (unsigned)(j + 2), bid, tid);
  }

  // ---- output: out[b][t]; cont is a GLOBAL any() over batches (ref semantics) ----
  if (bid == 0) {
    __shared__ int cseq[80];
    for (int i = tid; i < 80; i += TPB) cseq[i] = (i == 0) ? 1 : 0;
    __syncthreads();
    if (tid < 512) {
      const int t = (tid >> 3) + 1;        // 1..64
      const int bg = tid & 7;              // 4 batches each
      if (t <= maxiter) {
        int any = 0;
        for (int q = 0; q < 4; ++q) {
          const int b = bg * 4 + q;
          any |= (slots[b * SLOT_STRIDE + (t - 1)] > thr2_l[b]) ? 1 : 0;
        }
        if (any) atomicOr(&cseq[t], 1);
      }
    }
    __syncthreads();
    if (tid == 0) {
      int run = 1;
      for (int t = 1; t <= maxiter; ++t) { run &= cseq[t]; cseq[t] = run; }
    }
    __syncthreads();
    const int M1 = maxiter + 1;
    for (int idx = tid; idx < BS * M1; idx += TPB) {
      const int b = idx / M1, t = idx % M1;
      const float bn = sqrtf(bsum[b]);
      float val;
      if (t == 0) val = sqrtf(slots[b * SLOT_STRIDE]) / bn;
      else        val = cseq[t] ? sqrtf(slots[b * SLOT_STRIDE + t]) / bn : 0.0f;
      out[idx] = val;
    }
  }
}

extern "C" void kernel_launch(void* const* d_in, const int* in_sizes, int n_in,
                              void* d_out, int out_size, void* d_ws, size_t ws_size,
                              hipStream_t stream)
{
  (void)n_in; (void)ws_size;
  const float* A     = (const float*)d_in[0];   // ref uses only A[:1]
  const float* bvec  = (const float*)d_in[1];
  const float* rtol  = (const float*)d_in[3];   // d_in[2] = x_sol, unused by ref
  const float* theta = (const float*)d_in[4];
  float* out = (float*)d_out;
  float* ws  = (float*)d_ws;
  const int bs = in_sizes[3];                   // 32
  const int maxiter = out_size / bs - 1;        // 64

  // zero barrier counters / release flag / slot accumulators (graph-capturable)
  hipMemsetAsync(d_ws, 0, WS_ZERO_BYTES, stream);

  void* args[] = { (void*)&A, (void*)&bvec, (void*)&rtol, (void*)&theta,
                   (void*)&out, (void*)&ws, (void*)&maxiter };
  hipLaunchCooperativeKernel((void*)jacobi_kernel, dim3(NBLK), dim3(TPB),
                             args, 0, stream);
}